// Round 1
// 674.760 us; speedup vs baseline: 1.0789x; 1.0789x over previous
//
#include <hip/hip_runtime.h>
#include <math.h>

// ---------------- workspace layout (float offsets) ----------------
#define WS_ROWSUM_R 0u
#define WS_ROWSUM_I 131072u
#define WS_COLSUM_R 262144u
#define WS_COLSUM_I 393216u
#define WS_WF_R     524288u
#define WS_WF_I     655360u
#define WS_WT_R     786432u
#define WS_WT_I     917504u
#define WS_A2_R     1048576u
#define WS_A2_I     1049088u
#define WS_G_R      1049600u
#define WS_G_I      1050112u
#define WS_H_R      1050624u
#define WS_H_I      1051136u
#define WS_KC_R     1051648u   // 72 floats (collapsed conv kernel, real)
#define WS_KC_I     1051728u   // 72 floats
#define WS_C1       1051808u   // [2] : sum_o a1[o]*b3[o] per part

__device__ __forceinline__ float sigf(float v) { return 1.0f / (1.0f + expf(-v)); }

// ================= K1: row sums & col sums per (n,c), both parts =================
// grid 512 = n*8+c, block 256
__global__ __launch_bounds__(256) void k1_pool(const float* __restrict__ x,
                                               float* __restrict__ ws) {
  const int blk = blockIdx.x;
  const int n = blk >> 3, c = blk & 7;
  const int bb = n >> 3, gg = n & 7;
  const float4* x4 = (const float4*)(x + (((size_t)(bb * 64 + gg * 8 + c)) << 17));
  const int tid = threadIdx.x, w = tid >> 6, lane = tid & 63;
  __shared__ float ls_row[2][256];
  __shared__ float ls_col[2][4][256];
  float cr0 = 0.f, cr1 = 0.f, cr2 = 0.f, cr3 = 0.f;
  float ci0 = 0.f, ci1 = 0.f, ci2 = 0.f, ci3 = 0.f;
#pragma unroll 4
  for (int j = 0; j < 64; ++j) {
    const int f = w * 64 + j;
    const float4 v0 = x4[f * 128 + lane];        // cols 2*lane, 2*lane+1
    const float4 v1 = x4[f * 128 + 64 + lane];   // cols 128+2*lane, 128+2*lane+1
    cr0 += v0.x; ci0 += v0.y; cr1 += v0.z; ci1 += v0.w;
    cr2 += v1.x; ci2 += v1.y; cr3 += v1.z; ci3 += v1.w;
    float rr = (v0.x + v0.z) + (v1.x + v1.z);
    float ri = (v0.y + v0.w) + (v1.y + v1.w);
#pragma unroll
    for (int d = 32; d > 0; d >>= 1) { rr += __shfl_xor(rr, d); ri += __shfl_xor(ri, d); }
    if (lane == 0) { ls_row[0][f] = rr; ls_row[1][f] = ri; }
  }
  ls_col[0][w][2 * lane]           = cr0; ls_col[0][w][2 * lane + 1]       = cr1;
  ls_col[0][w][128 + 2 * lane]     = cr2; ls_col[0][w][128 + 2 * lane + 1] = cr3;
  ls_col[1][w][2 * lane]           = ci0; ls_col[1][w][2 * lane + 1]       = ci1;
  ls_col[1][w][128 + 2 * lane]     = ci2; ls_col[1][w][128 + 2 * lane + 1] = ci3;
  __syncthreads();
  const size_t ob = (size_t)blk * 256 + tid;
  ws[WS_ROWSUM_R + ob] = ls_row[0][tid];
  ws[WS_ROWSUM_I + ob] = ls_row[1][tid];
  ws[WS_COLSUM_R + ob] = ls_col[0][0][tid] + ls_col[0][1][tid] + ls_col[0][2][tid] + ls_col[0][3][tid];
  ws[WS_COLSUM_I + ob] = ls_col[1][0][tid] + ls_col[1][1][tid] + ls_col[1][2][tid] + ls_col[1][3][tid];
}

// ================= K2: 1x1 conv + sigmoids -> wf/wt ; a2 ; collapsed conv kernel =================
// grid 64 = n, block 256
__global__ __launch_bounds__(256) void k2_small(
    const float* __restrict__ x,
    const float* __restrict__ w1r, const float* __restrict__ b1r,
    const float* __restrict__ w1i, const float* __restrict__ b1i,
    const float* __restrict__ w3r, const float* __restrict__ b3r,
    const float* __restrict__ w3i, const float* __restrict__ b3i,
    const float* __restrict__ gnb_r, const float* __restrict__ gnb_i,
    float* __restrict__ ws) {
  const int n = blockIdx.x, tid = threadIdx.x;
  const size_t nb = (size_t)n * 2048;  // n*8*256
  __shared__ float s_w1[2][64], s_b1[2][8];
  if (tid < 64) { s_w1[0][tid] = w1r[tid]; s_w1[1][tid] = w1i[tid]; }
  if (tid < 8)  { s_b1[0][tid] = b1r[tid]; s_b1[1][tid] = b1i[tid]; }
  __syncthreads();
  float rawfr[8], rawfi[8], rawtr[8], rawti[8];
#pragma unroll
  for (int c = 0; c < 8; ++c) {
    rawfr[c] = ws[WS_ROWSUM_R + nb + c * 256 + tid];
    rawfi[c] = ws[WS_ROWSUM_I + nb + c * 256 + tid];
    rawtr[c] = ws[WS_COLSUM_R + nb + c * 256 + tid];
    rawti[c] = ws[WS_COLSUM_I + nb + c * 256 + tid];
  }
#pragma unroll
  for (int o = 0; o < 8; ++o) {
    float fr = 0.f, fi = 0.f, tr = 0.f, ti = 0.f;
#pragma unroll
    for (int c = 0; c < 8; ++c) {
      fr += s_w1[0][o * 8 + c] * rawfr[c];
      fi += s_w1[1][o * 8 + c] * rawfi[c];
      tr += s_w1[0][o * 8 + c] * rawtr[c];
      ti += s_w1[1][o * 8 + c] * rawti[c];
    }
    fr = fr * (1.f / 256.f) + s_b1[0][o];
    fi = fi * (1.f / 256.f) + s_b1[1][o];
    tr = tr * (1.f / 256.f) + s_b1[0][o];
    ti = ti * (1.f / 256.f) + s_b1[1][o];
    const float sfr = sigf(fr), sfi = sigf(fi), str_ = sigf(tr), sti = sigf(ti);
    ws[WS_WF_R + nb + o * 256 + tid] = sfr - sfi;
    ws[WS_WF_I + nb + o * 256 + tid] = sfi + sfr;
    ws[WS_WT_R + nb + o * 256 + tid] = str_ - sti;
    ws[WS_WT_I + nb + o * 256 + tid] = sti + str_;
  }
  // ---- totals per (part,c) ----
  const int w = tid >> 6, lane = tid & 63;
  __shared__ float red[16][4];
#pragma unroll
  for (int c = 0; c < 8; ++c) {
    float vr = rawfr[c], vi = rawfi[c];
#pragma unroll
    for (int d = 32; d > 0; d >>= 1) { vr += __shfl_xor(vr, d); vi += __shfl_xor(vi, d); }
    if (lane == 0) { red[c][w] = vr; red[8 + c][w] = vi; }
  }
  __syncthreads();
  __shared__ float Tot[2][8];
  if (tid < 16) Tot[tid >> 3][tid & 7] = red[tid][0] + red[tid][1] + red[tid][2] + red[tid][3];
  __syncthreads();
  // ---- shifted sums S(part,c,tap) via inclusion-exclusion ----
  __shared__ float S[2][8][9];
  if (tid < 144) {
    const int part = tid / 72, r = tid % 72, c = r / 9, tap = r % 9;
    const int dh = tap / 3 - 1, dw = tap % 3 - 1;
    float s = Tot[part][c];
    const size_t rbase = (part ? WS_ROWSUM_I : WS_ROWSUM_R) + nb + c * 256;
    const size_t cbase = (part ? WS_COLSUM_I : WS_COLSUM_R) + nb + c * 256;
    if (dh != 0) s -= ws[rbase + (dh < 0 ? 255 : 0)];
    if (dw != 0) s -= ws[cbase + (dw < 0 ? 255 : 0)];
    if (dh != 0 && dw != 0) {
      const int bb = n >> 3, gg = n & 7;
      const size_t xi = (((size_t)(bb * 64 + gg * 8 + c) * 65536) +
                         (size_t)(dh < 0 ? 255 : 0) * 256 + (dw < 0 ? 255 : 0)) * 2 + part;
      s += x[xi];
    }
    S[part][c][tap] = s;
  }
  __syncthreads();
  __shared__ float m2s[2][8];
  if (tid < 16) {
    const int part = tid >> 3, o = tid & 7;
    const float* w3 = part ? w3i : w3r;
    const float* b3 = part ? b3i : b3r;
    float acc = 0.f;
    for (int c = 0; c < 8; ++c)
      for (int tp = 0; tp < 9; ++tp)
        acc += w3[o * 72 + c * 9 + tp] * S[part][c][tp];
    m2s[part][o] = acc * (1.f / 65536.f) + b3[o];
  }
  __syncthreads();
  if (tid < 16) {
    const int part = tid >> 3, o = tid & 7;
    float mx = m2s[part][0];
    for (int k = 1; k < 8; ++k) mx = fmaxf(mx, m2s[part][k]);
    float den = 0.f;
    for (int k = 0; k < 8; ++k) den += expf(m2s[part][k] - mx);
    ws[(part ? WS_A2_I : WS_A2_R) + (size_t)n * 8 + o] = expf(m2s[part][o] - mx) / den;
  }
  // ---- n-independent pieces (block 0): a1 = softmax(gnb), collapsed kernel, C1 ----
  if (n == 0) {
    if (tid < 144) {
      const int part = tid / 72, r = tid % 72, c = r / 9, tap = r % 9;
      const float* w3 = part ? w3i : w3r;
      const float* gb = part ? gnb_i : gnb_r;
      float mx = gb[0]; for (int k = 1; k < 8; ++k) mx = fmaxf(mx, gb[k]);
      float den = 0.f; for (int k = 0; k < 8; ++k) den += expf(gb[k] - mx);
      float acc = 0.f;
      for (int o = 0; o < 8; ++o) acc += (expf(gb[o] - mx) / den) * w3[o * 72 + c * 9 + tap];
      ws[(part ? WS_KC_I : WS_KC_R) + c * 9 + tap] = acc;
    }
    if (tid < 2) {
      const int part = tid;
      const float* gb = part ? gnb_i : gnb_r;
      const float* b3 = part ? b3i : b3r;
      float mx = gb[0]; for (int k = 1; k < 8; ++k) mx = fmaxf(mx, gb[k]);
      float den = 0.f; for (int k = 0; k < 8; ++k) den += expf(gb[k] - mx);
      float acc = 0.f; for (int o = 0; o < 8; ++o) acc += (expf(gb[o] - mx) / den) * b3[o];
      ws[WS_C1 + part] = acc;
    }
  }
}

// ================= K3: GN stats of p = x*wf*wt per (n,c) -> g,h =================
// grid 512 = n*8+c, block 256
// float4 loads (16B/lane), 256 threads = 128 col-pairs x 2 row-halves, unroll 4
__global__ __launch_bounds__(256) void k3_stats(
    const float* __restrict__ x,
    const float* __restrict__ gnw_r, const float* __restrict__ gnb_r,
    const float* __restrict__ gnw_i, const float* __restrict__ gnb_i,
    float* __restrict__ ws) {
  const int blk = blockIdx.x, n = blk >> 3, c = blk & 7;
  const int bb = n >> 3, gg = n & 7;
  const float4* x4 = (const float4*)(x + (((size_t)(bb * 64 + gg * 8 + c)) << 17));
  const int tid = threadIdx.x;
  const int t = tid & 127, h = tid >> 7;   // col-pair, row-half
  const float* wfr = ws + WS_WF_R + (size_t)blk * 256;
  const float* wfi = ws + WS_WF_I + (size_t)blk * 256;
  const float wtr0 = ws[WS_WT_R + (size_t)blk * 256 + 2 * t];
  const float wtr1 = ws[WS_WT_R + (size_t)blk * 256 + 2 * t + 1];
  const float wti0 = ws[WS_WT_I + (size_t)blk * 256 + 2 * t];
  const float wti1 = ws[WS_WT_I + (size_t)blk * 256 + 2 * t + 1];
  float sr = 0.f, sr2 = 0.f, si = 0.f, si2 = 0.f;
#pragma unroll 4
  for (int f = h * 128; f < h * 128 + 128; ++f) {
    const float4 v = x4[(size_t)f * 128 + t];   // cols 2t (r,i), 2t+1 (r,i)
    const float wfrf = wfr[f], wfif = wfi[f];
    const float pr0 = v.x * wfrf * wtr0;
    const float pi0 = v.y * wfif * wti0;
    const float pr1 = v.z * wfrf * wtr1;
    const float pi1 = v.w * wfif * wti1;
    sr += pr0 + pr1; sr2 += pr0 * pr0 + pr1 * pr1;
    si += pi0 + pi1; si2 += pi0 * pi0 + pi1 * pi1;
  }
  const int w = tid >> 6, lane = tid & 63;
#pragma unroll
  for (int d = 32; d > 0; d >>= 1) {
    sr += __shfl_xor(sr, d); sr2 += __shfl_xor(sr2, d);
    si += __shfl_xor(si, d); si2 += __shfl_xor(si2, d);
  }
  __shared__ float red[4][4];
  if (lane == 0) { red[0][w] = sr; red[1][w] = sr2; red[2][w] = si; red[3][w] = si2; }
  __syncthreads();
  if (tid == 0) {
    const float S1 = red[0][0] + red[0][1] + red[0][2] + red[0][3];
    const float S2 = red[1][0] + red[1][1] + red[1][2] + red[1][3];
    const float T1 = red[2][0] + red[2][1] + red[2][2] + red[2][3];
    const float T2 = red[3][0] + red[3][1] + red[3][2] + red[3][3];
    const float mur = S1 * (1.f / 65536.f);
    const float varr = S2 * (1.f / 65536.f) - mur * mur;
    const float rsr = 1.f / sqrtf(varr + 1e-5f);
    const float mui = T1 * (1.f / 65536.f);
    const float vari = T2 * (1.f / 65536.f) - mui * mui;
    const float rsi = 1.f / sqrtf(vari + 1e-5f);
    const float a2r = ws[WS_A2_R + (size_t)n * 8 + c];
    const float a2i = ws[WS_A2_I + (size_t)n * 8 + c];
    ws[WS_G_R + blk] = a2r * gnw_r[c] * rsr;
    ws[WS_G_I + blk] = a2i * gnw_i[c] * rsi;
    ws[WS_H_R + blk] = a2r * (gnb_r[c] - gnw_r[c] * rsr * mur);
    ws[WS_H_I + blk] = a2i * (gnb_i[c] - gnw_i[c] * rsi * mui);
  }
}

// ================= K4: fused conv + gating + sigmoid + output =================
// grid 512 = n*8+seg (32 rows each), block 256 ; rolling 4-row LDS window (64 KiB)
// T14 software pipeline: global loads for iter j+1 issued during iter j (regs),
// only the ds_write sits between the barriers. Halo via shfl (no bank conflicts).
__global__ __launch_bounds__(256) void k4_out(const float* __restrict__ x,
                                              float* __restrict__ out,
                                              const float* __restrict__ ws) {
  const int blk = blockIdx.x;
  const int n = blk >> 3, seg = blk & 7;
  const int r0 = seg * 32;
  const int bb = n >> 3, gg = n & 7;
  const size_t cb = ((size_t)(bb * 64 + gg * 8)) << 17;  // float base of (n, ch0)
  const float* xp = x + cb;
  float* op = out + cb;
  const int tid = threadIdx.x;
  const int q = tid & 63, rp = tid >> 6, row_off = rp & 1, part = rp >> 1;

  __shared__ float win[2][8][4][256];   // [part][ch][slot][col] = 64 KiB exactly

  // ---- per-thread constants ----
  const float* KcP = ws + (part ? WS_KC_I : WS_KC_R);
  float kc[72];
#pragma unroll
  for (int k = 0; k < 72; ++k) kc[k] = KcP[k];
  const float* gP = ws + (part ? WS_G_I : WS_G_R) + (size_t)n * 8;
  const float* hP = ws + (part ? WS_H_I : WS_H_R) + (size_t)n * 8;
  float ggv[8];
  float Cn = ws[WS_C1 + part];
#pragma unroll
  for (int c = 0; c < 8; ++c) { ggv[c] = gP[c]; Cn += hP[c]; }
  const float* wfP = ws + (part ? WS_WF_I : WS_WF_R) + (size_t)n * 2048;
  const float* wtP = ws + (part ? WS_WT_I : WS_WT_R) + (size_t)n * 2048;
  float4 wt4[8];
#pragma unroll
  for (int c = 0; c < 8; ++c) wt4[c] = *(const float4*)&wtP[c * 256 + 4 * q];

  const int llr = tid >> 7;  // which of the 2 rows this thread loads
  const int g2 = tid & 127;  // col pair
  float4 pf[8];              // in-flight row pair (one row per thread, 8 channels)

  auto gissue = [&](int fr_base) {   // issue global loads -> pf
    const int fr = fr_base + llr;
    if (fr >= 0 && fr < 256) {
#pragma unroll
      for (int c = 0; c < 8; ++c)
        pf[c] = *(const float4*)&xp[(((size_t)c * 65536) + (size_t)fr * 256 + 2 * g2) * 2];
    } else {
#pragma unroll
      for (int c = 0; c < 8; ++c) pf[c] = make_float4(0.f, 0.f, 0.f, 0.f);
    }
  };
  auto lwrite = [&](int fr_base) {   // pf -> LDS window
    const int fr = fr_base + llr;
    const int slot = fr & 3;
#pragma unroll
    for (int c = 0; c < 8; ++c) {
      *(float2*)&win[0][c][slot][2 * g2] = make_float2(pf[c].x, pf[c].z);
      *(float2*)&win[1][c][slot][2 * g2] = make_float2(pf[c].y, pf[c].w);
    }
  };

  gissue(r0 - 1);          // rows r0-1, r0
  lwrite(r0 - 1);
  gissue(r0 + 1);          // rows r0+1, r0+2 in flight

  for (int j = 0; j < 16; ++j) {
    __syncthreads();              // WAR: prev iter's window reads complete
    lwrite(r0 + 2 * j + 1);       // data arrived ~1 iteration ago
    if (j < 15) gissue(r0 + 2 * j + 3);   // next pair: latency spans compute below
    __syncthreads();              // ds_writes visible
    const int f = r0 + 2 * j + row_off;
    float wv0 = Cn, wv1 = Cn, wv2 = Cn, wv3 = Cn;
    float4 xc4[8];
#pragma unroll
    for (int c = 0; c < 8; ++c) {
      const float* wc = &win[part][c][0][0];
      const float wfv = wfP[c * 256 + f];
      const float gw = ggv[c] * wfv;
#pragma unroll
      for (int dr = -1; dr <= 1; ++dr) {
        const int slot = (f + dr) & 3;
        const float* rowp = wc + slot * 256;
        const float4 m = *(const float4*)&rowp[4 * q];
        const float lsh = __shfl_up(m.w, 1);    // col 4q-1 from lane q-1
        const float rsh = __shfl_down(m.x, 1);  // col 4q+4 from lane q+1
        const float lft = q ? lsh : 0.f;
        const float rgt = (q < 63) ? rsh : 0.f;
        const float t0 = kc[c * 9 + (dr + 1) * 3 + 0];
        const float t1 = kc[c * 9 + (dr + 1) * 3 + 1];
        const float t2 = kc[c * 9 + (dr + 1) * 3 + 2];
        wv0 += t0 * lft + t1 * m.x + t2 * m.y;
        wv1 += t0 * m.x + t1 * m.y + t2 * m.z;
        wv2 += t0 * m.y + t1 * m.z + t2 * m.w;
        wv3 += t0 * m.z + t1 * m.w + t2 * rgt;
        if (dr == 0) {
          xc4[c] = m;
          wv0 += gw * wt4[c].x * m.x;
          wv1 += gw * wt4[c].y * m.y;
          wv2 += gw * wt4[c].z * m.z;
          wv3 += gw * wt4[c].w * m.w;
        }
      }
    }
    const float s0 = sigf(wv0), s1 = sigf(wv1), s2 = sigf(wv2), s3 = sigf(wv3);
#pragma unroll
    for (int c = 0; c < 8; ++c) {
      const size_t ob = (((size_t)c * 65536) + (size_t)f * 256 + 4 * q) * 2 + part;
      op[ob]     = xc4[c].x * s0;
      op[ob + 2] = xc4[c].y * s1;
      op[ob + 4] = xc4[c].z * s2;
      op[ob + 6] = xc4[c].w * s3;
    }
  }
}

extern "C" void kernel_launch(void* const* d_in, const int* in_sizes, int n_in,
                              void* d_out, int out_size, void* d_ws, size_t ws_size,
                              hipStream_t stream) {
  const float* x     = (const float*)d_in[0];
  const float* w1r   = (const float*)d_in[1];
  const float* b1r   = (const float*)d_in[2];
  const float* w1i   = (const float*)d_in[3];
  const float* b1i   = (const float*)d_in[4];
  const float* w3r   = (const float*)d_in[5];
  const float* b3r   = (const float*)d_in[6];
  const float* w3i   = (const float*)d_in[7];
  const float* b3i   = (const float*)d_in[8];
  const float* gnw_r = (const float*)d_in[9];
  const float* gnb_r = (const float*)d_in[10];
  const float* gnw_i = (const float*)d_in[11];
  const float* gnb_i = (const float*)d_in[12];
  float* out = (float*)d_out;
  float* ws  = (float*)d_ws;

  k1_pool <<<512, 256, 0, stream>>>(x, ws);
  k2_small<<<64,  256, 0, stream>>>(x, w1r, b1r, w1i, b1i, w3r, b3r, w3i, b3i, gnb_r, gnb_i, ws);
  k3_stats<<<512, 256, 0, stream>>>(x, gnw_r, gnb_r, gnw_i, gnb_i, ws);
  k4_out  <<<512, 256, 0, stream>>>(x, out, ws);
}